// Round 9
// baseline (17.522 us; speedup 1.0000x reference)
//
#include <hip/hip_runtime.h>
#include <math.h>

// ECT layer: ect[b,t,r] = sum_{n: batch[n]==b} sigmoid(8*(lin[r] - <x_n,v_t>))
// N=100000, D=3, T=64, R=64, B=128, lin = linspace(-1.1,1.1,64), d = 2.2/63.
//
// Algorithm (validated r4-r8): CIC-deposit nh onto a lin-aligned grid
// (160 bins + 63 pad), convolve with compile-time sigmoid taps (148, inline
// literals). r7 lesson: f32 LDS atomics are a slow serial FP-RMW path on
// gfx950 -> fixed-point u32 atomics (4x). r8: const taps + ds_read2 (-2.4us).
//
// Round-9 changes (deposit phase dominates):
//  - ONE packed ds_add_u64 per (node,dir) instead of two ds_add_u32: the two
//    CIC deposits hit adjacent bins (a,a+1); two parity-staggered u64 arrays
//    He[k]=(2k,2k+1), Ho[k]=(2k+1,2k+2) make every pair one aligned u64 word,
//    selected branch-free via the parity bit in the address. Reconstruction:
//    H[a] = He32[a] + Ho32[a-1] in the conversion pass. Exact (no carry:
//    sum <= 780*65536 << 2^32).
//  - 4-deep x preload: 4 independent float3 loads per outer iter, one wait
//    per 256 nodes (hides L2 latency that a 64-node loop exposes).

#define THREADS 256
#define TPB 4            // directions per block
#define TQ  16           // blocks per point cloud: TPB*TQ = 64 directions
#define PAD 63
#define STEPS 148        // conv taps: out[r] = sum_{j<148} W[j]*H[r+j]
#define ROW32 228        // u32/f32 elements per histogram row (228%32=4)
#define ROW64 114        // u64 words per row
#define HO_BASE64 (TPB * ROW64)   // Ho array offset in u64 words (456)

// ---- compile-time sigmoid tap table (folded 2^-16 fixed-point unscale) ----
constexpr double cexp_taylor(double r) {
    double s = 1.0, term = 1.0;
    for (int i = 1; i < 18; ++i) { term *= r / (double)i; s += term; }
    return s;
}
constexpr double cexp(double x) {             // |x| < 45
    const double LN2 = 0.69314718055994530942;
    const int n = (int)(x / LN2 + (x >= 0.0 ? 0.5 : -0.5));
    const double r = x - (double)n * LN2;
    double e = cexp_taylor(r);
    if (n >= 0) { for (int i = 0; i < n;  ++i) e *= 2.0; }
    else        { for (int i = 0; i < -n; ++i) e *= 0.5; }
    return e;
}
struct WTab {
    float w[STEPS];
    constexpr WTab() : w() {
        const double d = 2.2 / 63.0;
        for (int j = 0; j < STEPS; ++j) {
            const double z = 8.0 * d * (double)(111 - j);   // sigmoid argument
            w[j] = (float)(1.0 / ((1.0 + cexp(-z)) * 65536.0));
        }
    }
};
constexpr WTab WT;   // WT.w[j] folds as inline literals in unrolled fmas

// all-lane 64-ary lower_bound: first i with A[i] >= val (A ascending).
__device__ __forceinline__ int lb64(const int* __restrict__ A, int n, int val,
                                    int lane) {
    int lo = 0, hi = n;
    while (hi - lo > 64) {
        const long long span = hi - lo;
        const int p = lo + (int)((span * lane) >> 6);        // p0 = lo
        const unsigned long long m = __ballot(A[p] < val);   // contiguous ones
        const int c = __popcll(m);
        if (c == 0) { hi = lo; break; }                      // A[lo] >= val
        const int plast = lo + (int)((span * (c - 1)) >> 6);
        const int pnext = (c < 64) ? (lo + (int)((span * (long long)c) >> 6)) : hi;
        lo = plast + 1; hi = pnext;
    }
    const int span = hi - lo;
    const unsigned long long m = __ballot(lane < span && A[lo + lane] < val);
    return lo + __popcll(m);
}

__global__ __launch_bounds__(THREADS, 8) void ect_fused6_kernel(
    const float* __restrict__ x,      // [N,3]
    const float* __restrict__ v,      // [3,64]
    const int*   __restrict__ batch,  // [N] sorted 0..127
    float* __restrict__ out,          // [128,64,64]
    int n, float inv_d, float bias)
{
    __shared__ unsigned long long Hu[2 * TPB * ROW64];   // He rows | Ho rows

    const int tid  = threadIdx.x;
    const int wv   = tid >> 6;                   // wave 0..3
    const int lane = tid & 63;
    const int b    = blockIdx.x >> 4;            // / TQ
    const int tq   = blockIdx.x & (TQ - 1);

    // zero both histogram arrays (912 u64 / 256 threads ~ 4 ds_write_b64)
    for (int i = tid; i < 2 * TPB * ROW64; i += THREADS) Hu[i] = 0ull;

    // segment bounds (each wave duplicates; overlaps with init)
    const int s0 = lb64(batch, n, b, lane);
    const int s1 = lb64(batch, n, b + 1, lane);

    // deposit mapping: lane = (t_l, slot); block covers 64 nodes/iter
    const int t_l  = lane >> 4;                  // direction 0..3 within block
    const int slot = (lane & 15) + (wv << 4);    // node slot 0..63 across waves
    const int tbase = tq * TPB;
    const int t    = tbase + t_l;
    const float va = v[t], vb = v[64 + t], vc = v[128 + t];
    const int rowoff64 = t_l * ROW64;

    __syncthreads();

    // ---- phase 1: CIC deposit, ONE packed u64 atomic per (node,dir), ----
    // ---- 4-deep preload (256 nodes per outer iteration)              ----
    for (int base = s0; base < s1; base += 4 * 64) {
        float xs0[4], xs1[4], xs2[4];
        bool  ok[4];
#pragma unroll
        for (int k = 0; k < 4; ++k) {
            const int idx = base + (k << 6) + slot;
            ok[k] = (idx < s1);
            if (ok[k]) {
                const float3 xx = *(const float3*)(x + 3 * (size_t)idx);
                xs0[k] = xx.x; xs1[k] = xx.y; xs2[k] = xx.z;
            }
        }
#pragma unroll
        for (int k = 0; k < 4; ++k) {
            if (!ok[k]) continue;
            const float nh = fmaf(xs0[k], va, fmaf(xs1[k], vb, xs2[k] * vc));
            float bin = fmaf(nh, inv_d, bias);           // (nh - umin)/d
            bin = fminf(fmaxf(bin, 0.0f), 158.999f);     // tails saturate
            const float g0f = floorf(bin);
            const float fr  = bin - g0f;
            const int   a   = PAD + (int)g0f;            // 63..221
            const unsigned q1 = (unsigned)(fr * 65536.0f + 0.5f);
            const unsigned q0 = 65536u - q1;
            const unsigned long long val =
                (unsigned long long)q0 | ((unsigned long long)q1 << 32);
            // parity-staggered word: even a -> He[a/2], odd a -> Ho[(a-1)/2]
            const int w64 = (a >> 1) + rowoff64 + ((a & 1) ? HO_BASE64 : 0);
            atomicAdd(&Hu[w64], val);                    // ds_add_u64
        }
    }

    __syncthreads();

    // ---- phase 1.5: reconstruct + u32->f32 in place over He region ----
    // H[a] = He32[a] + Ho32[a-1]; scale 2^-16 folded into taps.
    {
        unsigned* He32 = (unsigned*)Hu;
        unsigned* Ho32 = (unsigned*)(Hu + HO_BASE64);
        if (tid < ROW32) {
#pragma unroll
            for (int tt = 0; tt < TPB; ++tt) {
                const int i = tt * ROW32 + tid;
                unsigned s = He32[i];
                if (tid > 0) s += Ho32[i - 1];
                ((float*)He32)[i] = (float)s;
            }
        }
    }

    __syncthreads();

    // ---- phase 2: conv. wave w -> direction row w; lane -> r ----
    const float* H = (const float*)Hu + wv * ROW32 + lane;   // single base VGPR
    float a0 = 0.f, a1 = 0.f;
#pragma unroll
    for (int j = 0; j < STEPS; j += 2) {
        a0 = fmaf(WT.w[j],     H[j],     a0);      // literal * ds_read2.lo
        a1 = fmaf(WT.w[j + 1], H[j + 1], a1);      // literal * ds_read2.hi
    }
    out[((size_t)b * 64 + tbase + wv) * 64 + lane] = a0 + a1;
}

extern "C" void kernel_launch(void* const* d_in, const int* in_sizes, int n_in,
                              void* d_out, int out_size, void* d_ws, size_t ws_size,
                              hipStream_t stream) {
    const float* x     = (const float*)d_in[0];
    const float* v     = (const float*)d_in[1];
    const int*   batch = (const int*)d_in[2];
    float*       out   = (float*)d_out;

    const int n = in_sizes[0] / 3;

    const double d = 2.2 / 63.0;
    const float inv_d = (float)(1.0 / d);          // 28.63636...
    const float bias  = 79.5f;                     // 31.5 + 48, exact

    hipLaunchKernelGGL(ect_fused6_kernel, dim3(128 * TQ), dim3(THREADS), 0,
                       stream, x, v, batch, out, n, inv_d, bias);
}